// Round 12
// baseline (8374.503 us; speedup 1.0000x reference)
//
#include <hip/hip_runtime.h>
#include <hip/hip_bf16.h>
#include <cstdio>

// ---------------------------------------------------------------------------
// HierarchicalDecoder: 4-layer LSTM stack, T=512, batch U=16.
// v11 = v10 with: cond -> direct single-line flag polls (no leader hop),
// c1 whole-K tiles (no LDS combine), c0 2 tiles/wave; dec unchanged except
// sleep-free worker polls. Write-once h-state + sc0sc1 write-through stores
// + cached data reads (no per-tick invalidate) as proven in v8-v10.
// ---------------------------------------------------------------------------

typedef __attribute__((ext_vector_type(8))) short short8;   // 8 x bf16
typedef __attribute__((ext_vector_type(4))) float f32x4;
typedef __attribute__((ext_vector_type(2))) unsigned int u32x2;
using bf16 = __hip_bfloat16;

__device__ __forceinline__ float bfraw2f(short s){
  return __uint_as_float(((unsigned)(unsigned short)s) << 16);
}
__device__ __forceinline__ unsigned bfbits(float f){
  __hip_bfloat16 h = __float2bfloat16(f);
  return (unsigned)*reinterpret_cast<unsigned short*>(&h);
}

// ---- barrier primitives ----------------------------------------------------
__device__ __forceinline__ void gbar_arrive(unsigned* flags, unsigned gen){
  asm volatile("s_waitcnt vmcnt(0)" ::: "memory");   // h-stores completed at LLC
  __syncthreads();                                   // all waves drained
  if (threadIdx.x == 0)
    __hip_atomic_store(&flags[blockIdx.x], gen,
                       __ATOMIC_RELAXED, __HIP_MEMORY_SCOPE_AGENT);
}
// direct poll of a small flag range (fits 1-2 cache lines), sleep-free
template<int BASE, int N>
__device__ __forceinline__ void dpoll(const unsigned* flags, unsigned gen){
  if (threadIdx.x < 64){
    const int l = threadIdx.x;
    for (;;){
      unsigned v = 0xFFFFFFFFu;
      if (l < N)
        v = __hip_atomic_load(&flags[BASE + l], __ATOMIC_RELAXED,
                              __HIP_MEMORY_SCOPE_AGENT);
      if (__all(v >= gen)) break;
    }
  }
  __syncthreads();
}
// hierarchical (for dec's 128-WG domains): leader polls flags, publishes wm
template<int BASE, int N>
__device__ __forceinline__ void lead_wait_pub(const unsigned* flags, unsigned* wm8,
                                              unsigned gen){
  if (threadIdx.x < 64){
    const int l = threadIdx.x;
    for (;;){
      bool ok = true;
#pragma unroll
      for (int k = 0; k < (N + 63) / 64; ++k){
        int idx = l + k * 64;
        if (idx < N)
          ok &= (__hip_atomic_load(&flags[BASE + idx], __ATOMIC_RELAXED,
                                   __HIP_MEMORY_SCOPE_AGENT) >= gen);
      }
      if (__all(ok)) break;
    }
    if (l < 8)
      __hip_atomic_store(&wm8[l * 16], gen, __ATOMIC_RELAXED,
                         __HIP_MEMORY_SCOPE_AGENT);
  }
  __syncthreads();
}
__device__ __forceinline__ void worker_wait(const unsigned* wm8, unsigned gen){
  if (threadIdx.x == 0){
    const unsigned* p = &wm8[(blockIdx.x & 7) * 16];
    while (__hip_atomic_load(p, __ATOMIC_RELAXED, __HIP_MEMORY_SCOPE_AGENT) < gen)
      ;
  }
  __syncthreads();
}

// ---- A-operand loads: plain cached (write-once protocol makes them safe) ---
template<int N>
__device__ __forceinline__ void ldA(const bf16* base, short8* av){
#pragma unroll
  for (int i = 0; i < N; ++i)
    av[i] = *(const short8*)(base + i * 32);
}
__device__ __forceinline__ void vm0(){
  asm volatile("s_waitcnt vmcnt(0)" ::: "memory");
  __builtin_amdgcn_sched_barrier(0);
}

// ---- LSTM gate math for one 16-col tile; packed 8B write-through h-store ---
__device__ __forceinline__ void gate_tile(const float v[4], float* c_st,
                                          int col, int kg, int jb,
                                          bf16* hrow, int Hl, float* hTrow)
{
  const int g = col & 3;
#pragma unroll
  for (int rr = 0; rr < 4; ++rr){
    float a = (g == 2) ? tanhf(v[rr]) : 1.f / (1.f + expf(-v[rr]));
    float x1 = __shfl_xor(a, 1);
    float x2 = __shfl_xor(a, 2);
    float x3 = __shfl_xor(x1, 2);
    float cn = x1 * c_st[rr] + a * x2;   // valid on g==0 lanes
    float hn = x3 * tanhf(cn);           // sig(o)*tanh(c)
    c_st[rr] = cn;
    float h4 = __shfl_xor(hn, 4), h8 = __shfl_xor(hn, 8), h12 = __shfl_xor(hn, 12);
    if (col == 0){
      int u = kg * 4 + rr;
      u32x2 pk;
      pk.x = bfbits(hn) | (bfbits(h4) << 16);
      pk.y = bfbits(h8) | (bfbits(h12) << 16);
      bf16* p = hrow + (size_t)u * Hl + jb;
      asm volatile("global_store_dwordx2 %0, %1, off sc0 sc1"
                   :: "v"(p), "v"(pk) : "memory");
      if (hTrow){
        f32x4 hv = {hn, h4, h8, h12};
        *(f32x4*)(hTrow + (size_t)u * Hl + jb) = hv;
      }
    }
  }
}

// ---- weight prep: permute rows to col'=4j+g, concat K, cvt bf16 ------------
__global__ void k_prep_w(const float* __restrict__ srcA, const float* __restrict__ srcB,
                         int K1, int K2, int H, bf16* __restrict__ dst)
{
  const int row = blockIdx.x;
  const int j = row >> 2, g = row & 3;
  const int Kt = K1 + K2;
  const float* sA = srcA + (size_t)(g * H + j) * K1;
  const float* sB = srcB ? srcB + (size_t)(g * H + j) * K2 : nullptr;
  bf16* d = dst + (size_t)row * Kt;
  for (int k = threadIdx.x; k < Kt; k += blockDim.x)
    d[k] = __float2bfloat16(k < K1 ? sA[k] : sB[k - K1]);
}

__global__ void k_prep_b(const float* __restrict__ src, int H, float* __restrict__ dst){
  int i = blockIdx.x * blockDim.x + threadIdx.x;
  if (i < 4 * H) dst[i] = src[(i & 3) * H + (i >> 2)];
}

__global__ void k_conv_bf(const float* __restrict__ src, bf16* __restrict__ dst, int n){
  int i = blockIdx.x * blockDim.x + threadIdx.x;
  if (i < n) dst[i] = __float2bfloat16(src[i]);
}

// ---- fc0 -------------------------------------------------------------------
__global__ void k_fc0(const float* __restrict__ z, const float* __restrict__ w,
                      const float* __restrict__ b, bf16* __restrict__ x)
{
  const int m = blockIdx.x;
  const int t = m >> 4, u = m & 15;
  const float* zr = z + (size_t)t * 512 + u * 32;
  float zv[32];
#pragma unroll
  for (int k = 0; k < 32; ++k) zv[k] = zr[k];
  for (int n = threadIdx.x; n < 512; n += 256){
    const float* wr = w + n * 32;
    float s = b[n];
#pragma unroll
    for (int k = 0; k < 32; ++k) s += zv[k] * wr[k];
    x[(size_t)m * 512 + n] = __float2bfloat16(tanhf(s));
  }
}

// ---- big GEMM for gx0 = x @ Wgx0'^T + bc0' ---------------------------------
__device__ __forceinline__ void gload16(const void* g, void* lds_wave_base){
  __builtin_amdgcn_global_load_lds((const __attribute__((address_space(1))) void*)g,
                                   (__attribute__((address_space(3))) void*)lds_wave_base,
                                   16, 0, 0);
}

__global__ __launch_bounds__(256) void k_gemm_gx0(const bf16* __restrict__ A,
                                                  const bf16* __restrict__ W,
                                                  const float* __restrict__ bias,
                                                  float* __restrict__ C)
{
  __shared__ bf16 Al[128 * 64];
  __shared__ bf16 Bl[128 * 64];
  const int tid = threadIdx.x, lane = tid & 63, wave = tid >> 6;
  const int bm = blockIdx.x & 63, bn = blockIdx.x >> 6;
  const int wm = wave >> 1, wn = wave & 1;
  const int col = lane & 15, kg = lane >> 4;

  f32x4 acc[4][4];
#pragma unroll
  for (int i = 0; i < 4; ++i)
#pragma unroll
    for (int q = 0; q < 4; ++q) acc[i][q] = f32x4{0.f, 0.f, 0.f, 0.f};

  const int r = tid >> 3, c8 = (tid & 7) * 8;
  for (int k0 = 0; k0 < 512; k0 += 64){
    const bf16* ga = A + (size_t)(bm * 128 + r) * 512 + k0 + c8;
    const bf16* gb = W + (size_t)(bn * 128 + r) * 512 + k0 + c8;
#pragma unroll
    for (int i = 0; i < 4; ++i){
      gload16(ga + (size_t)32 * i * 512, (char*)Al + (size_t)i * 4096 + wave * 1024);
      gload16(gb + (size_t)32 * i * 512, (char*)Bl + (size_t)i * 4096 + wave * 1024);
    }
    __syncthreads();
#pragma unroll
    for (int kb = 0; kb < 2; ++kb){
      short8 af[4], bfr[4];
#pragma unroll
      for (int i = 0; i < 4; ++i)
        af[i] = *(const short8*)&Al[(wm * 64 + i * 16 + col) * 64 + kb * 32 + kg * 8];
#pragma unroll
      for (int i = 0; i < 4; ++i)
        bfr[i] = *(const short8*)&Bl[(wn * 64 + i * 16 + col) * 64 + kb * 32 + kg * 8];
#pragma unroll
      for (int i = 0; i < 4; ++i)
#pragma unroll
        for (int q = 0; q < 4; ++q)
          acc[i][q] = __builtin_amdgcn_mfma_f32_16x16x32_bf16(af[i], bfr[q], acc[i][q], 0, 0, 0);
    }
    __syncthreads();
  }
#pragma unroll
  for (int i = 0; i < 4; ++i)
#pragma unroll
    for (int q = 0; q < 4; ++q){
      int cc = bn * 128 + wn * 64 + q * 16 + col;
      float bv = bias[cc];
#pragma unroll
      for (int rr = 0; rr < 4; ++rr){
        int rrow = bm * 128 + wm * 64 + i * 16 + kg * 4 + rr;
        C[(size_t)rrow * 2048 + cc] = acc[i][q][rr] + bv;
      }
    }
}

// ---- conductor: c0 = WG 0-7 (2 tiles/wave), c1 = WG 8-23 (whole-K tiles).
// Direct single-line flag polls; c1 prefetches h0-part after arrive. --------
__global__ __launch_bounds__(512, 1) void k_cond(
    const bf16* __restrict__ Wc0, const bf16* __restrict__ Wc1,
    const float* __restrict__ bc1, const float* __restrict__ gx0,
    bf16* h0seq, bf16* h1seq, float* hT0, float* hT1, unsigned* flags)
{
  const int wg = blockIdx.x, tid = threadIdx.x;
  const int lane = tid & 63, wave = tid >> 6;
  const int col = lane & 15, kg = lane >> 4, r = col;

  if (wg < 8){
    // ---------------- c0: 64 waves x 2 tiles, K=512 -------------------------
    const int gw = wg * 8 + wave;                        // 0..63
    int colp[2], jb[2];
#pragma unroll
    for (int p = 0; p < 2; ++p){ colp[p] = (gw * 2 + p) * 16 + col; jb[p] = (gw * 2 + p) * 4; }

    short8 breg[2][16];
#pragma unroll
    for (int p = 0; p < 2; ++p)
#pragma unroll
      for (int i = 0; i < 16; ++i)
        breg[p][i] = *(const short8*)(Wc0 + (size_t)colp[p] * 512 + i * 32 + kg * 8);
#pragma unroll
    for (int p = 0; p < 2; ++p)
#pragma unroll
      for (int i = 0; i < 16; ++i) asm volatile("" : "+v"(breg[p][i]));

    float c_st[2][4] = {{0.f,0.f,0.f,0.f},{0.f,0.f,0.f,0.f}};
    float gxv[2][4];
#pragma unroll
    for (int p = 0; p < 2; ++p)
#pragma unroll
      for (int rr = 0; rr < 4; ++rr)
        gxv[p][rr] = gx0[((size_t)(kg * 4 + rr)) * 2048 + colp[p]];

    for (int tick = 0; tick < 513; ++tick){
      const int t = tick;
      if (t < 512){
        short8 av[16];
        ldA<16>(h0seq + (size_t)t * 8192 + r * 512 + kg * 8, av);
        vm0();
        f32x4 a0 = {0.f,0.f,0.f,0.f}, a1 = {0.f,0.f,0.f,0.f};
#pragma unroll
        for (int i = 0; i < 16; ++i){
          a0 = __builtin_amdgcn_mfma_f32_16x16x32_bf16(av[i], breg[0][i], a0, 0, 0, 0);
          a1 = __builtin_amdgcn_mfma_f32_16x16x32_bf16(av[i], breg[1][i], a1, 0, 0, 0);
        }
        bf16* hrow = h0seq + (size_t)(t + 1) * 8192;
        float* hTp = (t == 511) ? hT0 : nullptr;
        float v0[4], v1[4];
#pragma unroll
        for (int rr = 0; rr < 4; ++rr){ v0[rr] = a0[rr] + gxv[0][rr]; v1[rr] = a1[rr] + gxv[1][rr]; }
        gate_tile(v0, c_st[0], col, kg, jb[0], hrow, 512, hTp);
        gate_tile(v1, c_st[1], col, kg, jb[1], hrow, 512, hTp);
      }
      gbar_arrive(flags, (unsigned)(tick + 1));
      if (tick + 1 < 512){
#pragma unroll
        for (int p = 0; p < 2; ++p)
#pragma unroll
          for (int rr = 0; rr < 4; ++rr)
            gxv[p][rr] = gx0[((size_t)(tick + 1) * 16 + kg * 4 + rr) * 2048 + colp[p]];
      }
      dpoll<0, 8>(flags, (unsigned)(tick + 1));
    }
  } else {
    // ---------------- c1: 128 waves x 1 tile, whole K=1024 ------------------
    const int gw = (wg - 8) * 8 + wave;                  // 0..127
    const int colp = gw * 16 + col;
    const int jb = gw * 4;

    short8 breg[32];
#pragma unroll
    for (int i = 0; i < 32; ++i)
      breg[i] = *(const short8*)(Wc1 + (size_t)colp * 1024 + i * 32 + kg * 8);
#pragma unroll
    for (int i = 0; i < 32; ++i) asm volatile("" : "+v"(breg[i]));

    const float bias = bc1[colp];
    float c_st[4] = {0.f, 0.f, 0.f, 0.f};
    f32x4 acc_pre = {0.f, 0.f, 0.f, 0.f};

    for (int tick = 0; tick < 513; ++tick){
      const int t = tick - 1;
      if (t >= 0){
        short8 av[16];
        ldA<16>(h1seq + (size_t)t * 8192 + r * 512 + kg * 8, av);
        vm0();
        f32x4 acc = acc_pre;                             // h0-part, prefetched
#pragma unroll
        for (int i = 0; i < 16; ++i)
          acc = __builtin_amdgcn_mfma_f32_16x16x32_bf16(av[i], breg[16 + i], acc, 0, 0, 0);
        float v[4];
#pragma unroll
        for (int rr = 0; rr < 4; ++rr) v[rr] = acc[rr] + bias;
        float* hTp = (t == 511) ? hT1 : nullptr;
        gate_tile(v, c_st, col, kg, jb, h1seq + (size_t)(t + 1) * 8192, 512, hTp);
      }
      gbar_arrive(flags, (unsigned)(tick + 1));
      if (tick < 512){
        dpoll<0, 8>(flags, (unsigned)(tick + 1));        // c0 done tick+1 -> h0 slot tick+1
        short8 av[16];
        ldA<16>(h0seq + (size_t)(tick + 1) * 8192 + r * 512 + kg * 8, av);
        vm0();
        acc_pre = f32x4{0.f, 0.f, 0.f, 0.f};
#pragma unroll
        for (int i = 0; i < 16; ++i)
          acc_pre = __builtin_amdgcn_mfma_f32_16x16x32_bf16(av[i], breg[i], acc_pre, 0, 0, 0);
      }
      dpoll<8, 16>(flags, (unsigned)(tick + 1));
    }
  }
}

// ---- hd0/hd1 = tanh(fc1(hT)) into decoder seq slot 0 -----------------------
__global__ void k_hd(const float* __restrict__ hT0, const float* __restrict__ hT1,
                     const float* __restrict__ w, const float* __restrict__ b,
                     bf16* __restrict__ d0s0, bf16* __restrict__ d1s0)
{
  int gid = blockIdx.x * 256 + threadIdx.x;
  int sel = gid >> 14;
  int u = (gid >> 10) & 15, n = gid & 1023;
  const float* h = (sel ? hT1 : hT0) + u * 512;
  const float* wr = w + (size_t)n * 512;
  float s = b[n];
  for (int k = 0; k < 512; ++k) s += h[k] * wr[k];
  (sel ? d1s0 : d0s0)[(size_t)u * 1024 + n] = __float2bfloat16(tanhf(s));
}

// ---- decoder: d0 = WG 0-127 (leader 0), d1 = WG 128-255 (leader 128).
// d0: static h1 frags prefetched; d1: d0n frags prefetched (chase). ----------
__global__ __launch_bounds__(512, 2) void k_dec(
    const bf16* __restrict__ Wd0, const bf16* __restrict__ Wd1,
    const float* __restrict__ bd0, const float* __restrict__ bd1,
    const bf16* __restrict__ h1seq, bf16* d0seq, bf16* d1seq,
    unsigned* flags, unsigned* wm)
{
  const int wg = blockIdx.x, tid = threadIdx.x;
  const int lane = tid & 63, wave = tid >> 6;
  const int col = lane & 15, kg = lane >> 4, r = col;
  const bool L0 = wg < 128;
  const int grp = wave >> 2, q = wave & 3;
  const int tileIdx = (L0 ? wg : wg - 128) * 2 + grp;    // [0,256)
  const int colp = tileIdx * 16 + col;                   // [0,4096)
  const int jb = tileIdx * 4;
  unsigned* wm0 = wm;         // d0 replicas
  unsigned* wm1 = wm + 128;   // d1 replicas
  __shared__ f32x4 part[2][3][64];

  short8 breg[16];
#pragma unroll
  for (int i = 0; i < 16; ++i) breg[i] = short8{0,0,0,0,0,0,0,0};
  if (L0){
    const bf16* W = Wd0 + (size_t)colp * 1536 + q * 384;
#pragma unroll
    for (int i = 0; i < 12; ++i) breg[i] = *(const short8*)(W + i * 32 + kg * 8);
  } else {
    const bf16* W = Wd1 + (size_t)colp * 2048 + q * 512;
#pragma unroll
    for (int i = 0; i < 16; ++i) breg[i] = *(const short8*)(W + i * 32 + kg * 8);
  }
#pragma unroll
  for (int i = 0; i < 16; ++i) asm volatile("" : "+v"(breg[i]));

  const float bias = L0 ? bd0[colp] : bd1[colp];
  float c_st[4] = {0.f, 0.f, 0.f, 0.f};
  f32x4 acc_pre = {0.f, 0.f, 0.f, 0.f};

  // d0 prologue: prefetch static h1 fragments for t = 0 (h1seq is complete)
  if (L0){
    if (q == 0){
      short8 av[12];
      ldA<12>(h1seq + (size_t)1 * 8192 + r * 512 + kg * 8, av);
      vm0();
#pragma unroll
      for (int i = 0; i < 12; ++i)
        acc_pre = __builtin_amdgcn_mfma_f32_16x16x32_bf16(av[i], breg[i], acc_pre, 0, 0, 0);
    } else if (q == 1){
      short8 av[4];
      ldA<4>(h1seq + (size_t)1 * 8192 + r * 512 + kg * 8 + 384, av);
      vm0();
#pragma unroll
      for (int i = 0; i < 4; ++i)
        acc_pre = __builtin_amdgcn_mfma_f32_16x16x32_bf16(av[i], breg[i], acc_pre, 0, 0, 0);
    }
  }

  for (int tick = 0; tick < 513; ++tick){
    const int t = tick - (L0 ? 0 : 1);
    const bool active = (t >= 0 && t < 512);
    f32x4 acc = {0.f, 0.f, 0.f, 0.f};
    if (active){
      short8 av[16];
      if (L0){
        const bf16* d0p = d0seq + (size_t)t * 16384 + r * 1024 + kg * 8;
        if      (q == 0)  acc = acc_pre;                 // 12 static frags done
        else if (q == 1){
          ldA<8>(d0p, av);
          vm0();
          acc = acc_pre;                                 // 4 static frags done
#pragma unroll
          for (int i = 0; i < 8; ++i)
            acc = __builtin_amdgcn_mfma_f32_16x16x32_bf16(av[i], breg[4 + i], acc, 0, 0, 0);
        } else {
          ldA<12>(d0p + (q == 2 ? 256 : 640), av);
          vm0();
#pragma unroll
          for (int i = 0; i < 12; ++i)
            acc = __builtin_amdgcn_mfma_f32_16x16x32_bf16(av[i], breg[i], acc, 0, 0, 0);
        }
      } else {
        if (q < 2){
          acc = acc_pre;                                 // d0n half, prefetched
        } else {
          const bf16* d1c = d1seq + (size_t)t * 16384 + r * 1024 + kg * 8;
          ldA<16>(d1c + (q == 3 ? 512 : 0), av);
          vm0();
#pragma unroll
          for (int i = 0; i < 16; ++i)
            acc = __builtin_amdgcn_mfma_f32_16x16x32_bf16(av[i], breg[i], acc, 0, 0, 0);
        }
      }
      if (q != 0) part[grp][q - 1][lane] = acc;
    }
    __syncthreads();
    if (active && q == 0){
      f32x4 p0 = part[grp][0][lane], p1 = part[grp][1][lane], p2 = part[grp][2][lane];
      float v[4];
#pragma unroll
      for (int rr = 0; rr < 4; ++rr) v[rr] = acc[rr] + p0[rr] + p1[rr] + p2[rr] + bias;
      bf16* hrow = (L0 ? d0seq : d1seq) + (size_t)(t + 1) * 16384;
      gate_tile(v, c_st, col, kg, jb, hrow, 1024, nullptr);
    }
    gbar_arrive(flags, (unsigned)(tick + 1));
    if (L0){
      if (tick + 1 < 512){                               // prefetch static h1 for t'=tick+1
        if (q == 0){
          short8 av[12];
          ldA<12>(h1seq + (size_t)(tick + 2) * 8192 + r * 512 + kg * 8, av);
          vm0();
          acc_pre = f32x4{0.f, 0.f, 0.f, 0.f};
#pragma unroll
          for (int i = 0; i < 12; ++i)
            acc_pre = __builtin_amdgcn_mfma_f32_16x16x32_bf16(av[i], breg[i], acc_pre, 0, 0, 0);
        } else if (q == 1){
          short8 av[4];
          ldA<4>(h1seq + (size_t)(tick + 2) * 8192 + r * 512 + kg * 8 + 384, av);
          vm0();
          acc_pre = f32x4{0.f, 0.f, 0.f, 0.f};
#pragma unroll
          for (int i = 0; i < 4; ++i)
            acc_pre = __builtin_amdgcn_mfma_f32_16x16x32_bf16(av[i], breg[i], acc_pre, 0, 0, 0);
        }
      }
      if (wg == 0) lead_wait_pub<0, 128>(flags, wm0, (unsigned)(tick + 1));
      else         worker_wait(wm0, (unsigned)(tick + 1));
    } else {
      if (tick < 512){                                   // prefetch d0n for t'=tick
        worker_wait(wm0, (unsigned)(tick + 1));          // d0seq slot tick+1 ready
        if (q < 2){
          short8 av[16];
          ldA<16>(d0seq + (size_t)(tick + 1) * 16384 + r * 1024 + kg * 8 + q * 512, av);
          vm0();
          acc_pre = f32x4{0.f, 0.f, 0.f, 0.f};
#pragma unroll
          for (int i = 0; i < 16; ++i)
            acc_pre = __builtin_amdgcn_mfma_f32_16x16x32_bf16(av[i], breg[i], acc_pre, 0, 0, 0);
        }
      }
      if (wg == 128) lead_wait_pub<128, 128>(flags, wm1, (unsigned)(tick + 1));
      else           worker_wait(wm1, (unsigned)(tick + 1));
    }
  }
}

// ---- logits ---------------------------------------------------------------
__global__ __launch_bounds__(256) void k_logits(const bf16* __restrict__ d1seq,
                                                const bf16* __restrict__ ow,
                                                const float* __restrict__ ob,
                                                float* __restrict__ logits)
{
  const int u = blockIdx.x >> 4, tb = blockIdx.x & 15;
  __shared__ bf16 rows[32][1024];
  const int tid = threadIdx.x;
  for (int idx = tid; idx < 4096; idx += 256){
    int tl = idx >> 7, seg = idx & 127;
    *(short8*)&rows[tl][seg * 8] =
      *(const short8*)(d1seq + ((size_t)(tb * 32 + tl + 1) * 16 + u) * 1024 + seg * 8);
  }
  __syncthreads();
  for (int p = tid; p < 512; p += 256){
    int tl = p >> 4, o = p & 15;
    const bf16* wr = ow + (size_t)o * 1024;
    float s = 0.f;
    for (int k = 0; k < 1024; k += 8){
      short8 av = *(const short8*)&rows[tl][k];
      short8 wv = *(const short8*)(wr + k);
#pragma unroll
      for (int e = 0; e < 8; ++e) s += bfraw2f(av[e]) * bfraw2f(wv[e]);
    }
    logits[((size_t)u * 16 + o) * 512 + tb * 32 + tl] = s + ob[o];
  }
}

// ---- softmax over t per (u,o); out[t][u*16+o] ------------------------------
__global__ __launch_bounds__(256) void k_softmax(const float* __restrict__ logits,
                                                 float* __restrict__ out)
{
  const int u = blockIdx.x >> 4, o = blockIdx.x & 15;
  const float* L = logits + ((size_t)u * 16 + o) * 512;
  const int tid = threadIdx.x;
  float v0 = L[tid], v1 = L[tid + 256];
  float m = fmaxf(v0, v1);
  for (int d = 1; d < 64; d <<= 1) m = fmaxf(m, __shfl_xor(m, d));
  __shared__ float red[4], red2[4];
  if ((tid & 63) == 0) red[tid >> 6] = m;
  __syncthreads();
  m = fmaxf(fmaxf(red[0], red[1]), fmaxf(red[2], red[3]));
  float e0 = expf(v0 - m), e1 = expf(v1 - m);
  float s = e0 + e1;
  for (int d = 1; d < 64; d <<= 1) s += __shfl_xor(s, d);
  if ((tid & 63) == 0) red2[tid >> 6] = s;
  __syncthreads();
  s = red2[0] + red2[1] + red2[2] + red2[3];
  float inv = 1.f / s;
  out[(size_t)tid * 256 + u * 16 + o] = e0 * inv;
  out[(size_t)(tid + 256) * 256 + u * 16 + o] = e1 * inv;
}

// ---------------------------------------------------------------------------
extern "C" void kernel_launch(void* const* d_in, const int* in_sizes, int n_in,
                              void* d_out, int out_size, void* d_ws, size_t ws_size,
                              hipStream_t stream)
{
  const float* z      = (const float*)d_in[0];
  const float* fc0_w  = (const float*)d_in[1];
  const float* fc0_b  = (const float*)d_in[2];
  const float* fc1_w  = (const float*)d_in[3];
  const float* fc1_b  = (const float*)d_in[4];
  const float* c_wih0 = (const float*)d_in[5];
  const float* c_whh0 = (const float*)d_in[6];
  const float* c_b0   = (const float*)d_in[7];
  const float* c_wih1 = (const float*)d_in[8];
  const float* c_whh1 = (const float*)d_in[9];
  const float* c_b1   = (const float*)d_in[10];
  const float* d_wih0 = (const float*)d_in[11];
  const float* d_whh0 = (const float*)d_in[12];
  const float* d_b0   = (const float*)d_in[13];
  const float* d_wih1 = (const float*)d_in[14];
  const float* d_whh1 = (const float*)d_in[15];
  const float* d_b1   = (const float*)d_in[16];
  const float* out_w  = (const float*)d_in[17];
  const float* out_b  = (const float*)d_in[18];

  char* p = (char*)d_ws;
  auto alloc = [&](size_t bytes) -> char* {
    char* r = p; p += (bytes + 255) & ~(size_t)255; return r;
  };
  bf16*  Wgx0p  = (bf16*)alloc(2048ull * 512 * 2);
  bf16*  Wc0p   = (bf16*)alloc(2048ull * 512 * 2);
  bf16*  Wc1p   = (bf16*)alloc(2048ull * 1024 * 2);
  bf16*  Wd0p   = (bf16*)alloc(4096ull * 1536 * 2);
  bf16*  Wd1p   = (bf16*)alloc(4096ull * 2048 * 2);
  float* bc0p   = (float*)alloc(2048 * 4);
  float* bc1p   = (float*)alloc(2048 * 4);
  float* bd0p   = (float*)alloc(4096 * 4);
  float* bd1p   = (float*)alloc(4096 * 4);
  bf16*  outwbf = (bf16*)alloc(16384 * 2);
  bf16*  x      = (bf16*)alloc(8192ull * 512 * 2);
  float* gx0    = (float*)alloc(8192ull * 2048 * 4);
  bf16*  h0seq  = (bf16*)alloc(513ull * 16 * 512 * 2);
  bf16*  h1seq  = (bf16*)alloc(513ull * 16 * 512 * 2);
  bf16*  d0seq  = (bf16*)alloc(513ull * 16 * 1024 * 2);
  bf16*  d1seq  = (bf16*)alloc(513ull * 16 * 1024 * 2);
  float* hT0    = (float*)alloc(16 * 512 * 4);
  float* hT1    = (float*)alloc(16 * 512 * 4);
  float* logits = (float*)alloc(16ull * 16 * 512 * 4);
  unsigned* flagC = (unsigned*)alloc(64 * 4);
  unsigned* flagD = (unsigned*)alloc(256 * 4);
  unsigned* wmD   = (unsigned*)alloc(1024);
  if ((size_t)(p - (char*)d_ws) > ws_size){
    fprintf(stderr, "kernel_launch: ws too small (%zu needed, %zu given)\n",
            (size_t)(p - (char*)d_ws), ws_size);
    return;
  }

  hipMemsetAsync(flagC, 0, 64 * 4, stream);
  hipMemsetAsync(flagD, 0, 256 * 4, stream);
  hipMemsetAsync(wmD, 0, 1024, stream);
  hipMemsetAsync(h0seq, 0, 16 * 512 * 2, stream);
  hipMemsetAsync(h1seq, 0, 16 * 512 * 2, stream);

  k_prep_w<<<2048, 256, 0, stream>>>(c_wih0, nullptr, 512, 0,   512, Wgx0p);
  k_prep_w<<<2048, 256, 0, stream>>>(c_whh0, nullptr, 512, 0,   512, Wc0p);
  k_prep_w<<<2048, 256, 0, stream>>>(c_wih1, c_whh1, 512, 512,  512, Wc1p);
  k_prep_w<<<4096, 256, 0, stream>>>(d_wih0, d_whh0, 512, 1024, 1024, Wd0p);
  k_prep_w<<<4096, 256, 0, stream>>>(d_wih1, d_whh1, 1024, 1024, 1024, Wd1p);
  k_prep_b<<<8,  256, 0, stream>>>(c_b0, 512,  bc0p);
  k_prep_b<<<8,  256, 0, stream>>>(c_b1, 512,  bc1p);
  k_prep_b<<<16, 256, 0, stream>>>(d_b0, 1024, bd0p);
  k_prep_b<<<16, 256, 0, stream>>>(d_b1, 1024, bd1p);
  k_conv_bf<<<64, 256, 0, stream>>>(out_w, outwbf, 16 * 1024);

  k_fc0<<<8192, 256, 0, stream>>>(z, fc0_w, fc0_b, x);
  k_gemm_gx0<<<1024, 256, 0, stream>>>(x, Wgx0p, bc0p, gx0);

  k_cond<<<24, 512, 0, stream>>>(Wc0p, Wc1p, bc1p, gx0, h0seq, h1seq, hT0, hT1, flagC);
  k_hd<<<128, 256, 0, stream>>>(hT0, hT1, fc1_w, fc1_b, d0seq, d1seq);
  k_dec<<<256, 512, 0, stream>>>(Wd0p, Wd1p, bd0p, bd1p, h1seq, d0seq, d1seq, flagD, wmD);

  k_logits<<<256, 256, 0, stream>>>(d1seq, outwbf, out_b, logits);
  k_softmax<<<256, 256, 0, stream>>>(logits, (float*)d_out);
}

// Round 13
// 7076.470 us; speedup vs baseline: 1.1834x; 1.1834x over previous
//
#include <hip/hip_runtime.h>
#include <hip/hip_bf16.h>
#include <cstdio>

// ---------------------------------------------------------------------------
// HierarchicalDecoder: 4-layer LSTM stack, T=512, batch U=16.
// v12 = v10 (best: 6869us) with ONE change: conductor barriers use direct
// sleep-free line-polls (c0: 1 flag line, c1: 2 lines; chase polls c0's line
// directly) instead of the leader->watermark hop. Decoder identical to v10.
// Protocol: write-once h-state, sc0sc1 write-through stores, cached reads,
// no per-tick invalidate, 16 weight frags per wave (no spill).
// ---------------------------------------------------------------------------

typedef __attribute__((ext_vector_type(8))) short short8;   // 8 x bf16
typedef __attribute__((ext_vector_type(4))) float f32x4;
typedef __attribute__((ext_vector_type(2))) unsigned int u32x2;
using bf16 = __hip_bfloat16;

__device__ __forceinline__ float bfraw2f(short s){
  return __uint_as_float(((unsigned)(unsigned short)s) << 16);
}
__device__ __forceinline__ unsigned bfbits(float f){
  __hip_bfloat16 h = __float2bfloat16(f);
  return (unsigned)*reinterpret_cast<unsigned short*>(&h);
}

// ---- barrier primitives ----------------------------------------------------
__device__ __forceinline__ void gbar_arrive(unsigned* flags, unsigned gen){
  asm volatile("s_waitcnt vmcnt(0)" ::: "memory");   // h-stores completed at LLC
  __syncthreads();                                   // all waves drained
  if (threadIdx.x == 0)
    __hip_atomic_store(&flags[blockIdx.x], gen,
                       __ATOMIC_RELAXED, __HIP_MEMORY_SCOPE_AGENT);
}
// direct poll of a small flag range (1-2 cache lines), sleep-free
template<int BASE, int N>
__device__ __forceinline__ void dpoll(const unsigned* flags, unsigned gen){
  if (threadIdx.x < 64){
    const int l = threadIdx.x;
    for (;;){
      unsigned v = 0xFFFFFFFFu;
      if (l < N)
        v = __hip_atomic_load(&flags[BASE + l], __ATOMIC_RELAXED,
                              __HIP_MEMORY_SCOPE_AGENT);
      if (__all(v >= gen)) break;
    }
  }
  __syncthreads();
}
// hierarchical (dec's 128-WG domains): leader polls flags, publishes wm
template<int BASE, int N>
__device__ __forceinline__ void lead_wait_pub(const unsigned* flags, unsigned* wm8,
                                              unsigned gen){
  if (threadIdx.x < 64){
    const int l = threadIdx.x;
    for (;;){
      bool ok = true;
#pragma unroll
      for (int k = 0; k < (N + 63) / 64; ++k){
        int idx = l + k * 64;
        if (idx < N)
          ok &= (__hip_atomic_load(&flags[BASE + idx], __ATOMIC_RELAXED,
                                   __HIP_MEMORY_SCOPE_AGENT) >= gen);
      }
      if (__all(ok)) break;
    }
    if (l < 8)
      __hip_atomic_store(&wm8[l * 16], gen, __ATOMIC_RELAXED,
                         __HIP_MEMORY_SCOPE_AGENT);
  }
  __syncthreads();
}
__device__ __forceinline__ void worker_wait(const unsigned* wm8, unsigned gen){
  if (threadIdx.x == 0){
    const unsigned* p = &wm8[(blockIdx.x & 7) * 16];
    while (__hip_atomic_load(p, __ATOMIC_RELAXED, __HIP_MEMORY_SCOPE_AGENT) < gen)
      __builtin_amdgcn_s_sleep(1);
  }
  __syncthreads();
}

// ---- A-operand loads: plain cached (write-once protocol makes them safe) ---
template<int N>
__device__ __forceinline__ void ldA(const bf16* base, short8* av){
#pragma unroll
  for (int i = 0; i < N; ++i)
    av[i] = *(const short8*)(base + i * 32);
}
__device__ __forceinline__ void vm0(){
  asm volatile("s_waitcnt vmcnt(0)" ::: "memory");
  __builtin_amdgcn_sched_barrier(0);
}

// ---- LSTM gate math for one 16-col tile; packed 8B write-through h-store ---
__device__ __forceinline__ void gate_tile(const float v[4], float* c_st,
                                          int col, int kg, int jb,
                                          bf16* hrow, int Hl, float* hTrow)
{
  const int g = col & 3;
#pragma unroll
  for (int rr = 0; rr < 4; ++rr){
    float a = (g == 2) ? tanhf(v[rr]) : 1.f / (1.f + expf(-v[rr]));
    float x1 = __shfl_xor(a, 1);
    float x2 = __shfl_xor(a, 2);
    float x3 = __shfl_xor(x1, 2);
    float cn = x1 * c_st[rr] + a * x2;   // valid on g==0 lanes
    float hn = x3 * tanhf(cn);           // sig(o)*tanh(c)
    c_st[rr] = cn;
    float h4 = __shfl_xor(hn, 4), h8 = __shfl_xor(hn, 8), h12 = __shfl_xor(hn, 12);
    if (col == 0){
      int u = kg * 4 + rr;
      u32x2 pk;
      pk.x = bfbits(hn) | (bfbits(h4) << 16);
      pk.y = bfbits(h8) | (bfbits(h12) << 16);
      bf16* p = hrow + (size_t)u * Hl + jb;
      asm volatile("global_store_dwordx2 %0, %1, off sc0 sc1"
                   :: "v"(p), "v"(pk) : "memory");
      if (hTrow){
        f32x4 hv = {hn, h4, h8, h12};
        *(f32x4*)(hTrow + (size_t)u * Hl + jb) = hv;
      }
    }
  }
}

// ---- weight prep: permute rows to col'=4j+g, concat K, cvt bf16 ------------
__global__ void k_prep_w(const float* __restrict__ srcA, const float* __restrict__ srcB,
                         int K1, int K2, int H, bf16* __restrict__ dst)
{
  const int row = blockIdx.x;
  const int j = row >> 2, g = row & 3;
  const int Kt = K1 + K2;
  const float* sA = srcA + (size_t)(g * H + j) * K1;
  const float* sB = srcB ? srcB + (size_t)(g * H + j) * K2 : nullptr;
  bf16* d = dst + (size_t)row * Kt;
  for (int k = threadIdx.x; k < Kt; k += blockDim.x)
    d[k] = __float2bfloat16(k < K1 ? sA[k] : sB[k - K1]);
}

__global__ void k_prep_b(const float* __restrict__ src, int H, float* __restrict__ dst){
  int i = blockIdx.x * blockDim.x + threadIdx.x;
  if (i < 4 * H) dst[i] = src[(i & 3) * H + (i >> 2)];
}

__global__ void k_conv_bf(const float* __restrict__ src, bf16* __restrict__ dst, int n){
  int i = blockIdx.x * blockDim.x + threadIdx.x;
  if (i < n) dst[i] = __float2bfloat16(src[i]);
}

// ---- fc0 -------------------------------------------------------------------
__global__ void k_fc0(const float* __restrict__ z, const float* __restrict__ w,
                      const float* __restrict__ b, bf16* __restrict__ x)
{
  const int m = blockIdx.x;
  const int t = m >> 4, u = m & 15;
  const float* zr = z + (size_t)t * 512 + u * 32;
  float zv[32];
#pragma unroll
  for (int k = 0; k < 32; ++k) zv[k] = zr[k];
  for (int n = threadIdx.x; n < 512; n += 256){
    const float* wr = w + n * 32;
    float s = b[n];
#pragma unroll
    for (int k = 0; k < 32; ++k) s += zv[k] * wr[k];
    x[(size_t)m * 512 + n] = __float2bfloat16(tanhf(s));
  }
}

// ---- big GEMM for gx0 = x @ Wgx0'^T + bc0' ---------------------------------
__device__ __forceinline__ void gload16(const void* g, void* lds_wave_base){
  __builtin_amdgcn_global_load_lds((const __attribute__((address_space(1))) void*)g,
                                   (__attribute__((address_space(3))) void*)lds_wave_base,
                                   16, 0, 0);
}

__global__ __launch_bounds__(256) void k_gemm_gx0(const bf16* __restrict__ A,
                                                  const bf16* __restrict__ W,
                                                  const float* __restrict__ bias,
                                                  float* __restrict__ C)
{
  __shared__ bf16 Al[128 * 64];
  __shared__ bf16 Bl[128 * 64];
  const int tid = threadIdx.x, lane = tid & 63, wave = tid >> 6;
  const int bm = blockIdx.x & 63, bn = blockIdx.x >> 6;
  const int wm = wave >> 1, wn = wave & 1;
  const int col = lane & 15, kg = lane >> 4;

  f32x4 acc[4][4];
#pragma unroll
  for (int i = 0; i < 4; ++i)
#pragma unroll
    for (int q = 0; q < 4; ++q) acc[i][q] = f32x4{0.f, 0.f, 0.f, 0.f};

  const int r = tid >> 3, c8 = (tid & 7) * 8;
  for (int k0 = 0; k0 < 512; k0 += 64){
    const bf16* ga = A + (size_t)(bm * 128 + r) * 512 + k0 + c8;
    const bf16* gb = W + (size_t)(bn * 128 + r) * 512 + k0 + c8;
#pragma unroll
    for (int i = 0; i < 4; ++i){
      gload16(ga + (size_t)32 * i * 512, (char*)Al + (size_t)i * 4096 + wave * 1024);
      gload16(gb + (size_t)32 * i * 512, (char*)Bl + (size_t)i * 4096 + wave * 1024);
    }
    __syncthreads();
#pragma unroll
    for (int kb = 0; kb < 2; ++kb){
      short8 af[4], bfr[4];
#pragma unroll
      for (int i = 0; i < 4; ++i)
        af[i] = *(const short8*)&Al[(wm * 64 + i * 16 + col) * 64 + kb * 32 + kg * 8];
#pragma unroll
      for (int i = 0; i < 4; ++i)
        bfr[i] = *(const short8*)&Bl[(wn * 64 + i * 16 + col) * 64 + kb * 32 + kg * 8];
#pragma unroll
      for (int i = 0; i < 4; ++i)
#pragma unroll
        for (int q = 0; q < 4; ++q)
          acc[i][q] = __builtin_amdgcn_mfma_f32_16x16x32_bf16(af[i], bfr[q], acc[i][q], 0, 0, 0);
    }
    __syncthreads();
  }
#pragma unroll
  for (int i = 0; i < 4; ++i)
#pragma unroll
    for (int q = 0; q < 4; ++q){
      int cc = bn * 128 + wn * 64 + q * 16 + col;
      float bv = bias[cc];
#pragma unroll
      for (int rr = 0; rr < 4; ++rr){
        int rrow = bm * 128 + wm * 64 + i * 16 + kg * 4 + rr;
        C[(size_t)rrow * 2048 + cc] = acc[i][q][rr] + bv;
      }
    }
}

// ---- conductor: c0 = WG 0-15 (flags 0-15, 1 line), c1 = WG 16-47 (flags
// 16-47, 2 lines). Direct sleep-free polls; c1 prefetches h0-part (chase
// polls c0's line directly). Dataflow identical to v10. ---------------------
__global__ __launch_bounds__(512, 2) void k_cond(
    const bf16* __restrict__ Wc0, const bf16* __restrict__ Wc1,
    const float* __restrict__ bc1, const float* __restrict__ gx0,
    bf16* h0seq, bf16* h1seq, float* hT0, float* hT1, unsigned* flags)
{
  const int wg = blockIdx.x, tid = threadIdx.x;
  const int lane = tid & 63, wave = tid >> 6;
  const int col = lane & 15, kg = lane >> 4;
  const int r = col;
  const bool L0 = wg < 16;
  __shared__ f32x4 part[4][64];

  int tileIdx, half = 0;
  if (L0) tileIdx = wg * 8 + wave;                       // [0,128)
  else  { tileIdx = (wg - 16) * 4 + (wave >> 1); half = wave & 1; }
  const int colp = tileIdx * 16 + col;                   // [0,2048)
  const int jb = tileIdx * 4;

  short8 breg[16];
  {
    const bf16* W = L0 ? (Wc0 + (size_t)colp * 512)
                       : (Wc1 + (size_t)colp * 1024 + half * 512);
#pragma unroll
    for (int i = 0; i < 16; ++i) breg[i] = *(const short8*)(W + i * 32 + kg * 8);
  }
#pragma unroll
  for (int i = 0; i < 16; ++i) asm volatile("" : "+v"(breg[i]));

  const float bias = L0 ? 0.f : bc1[colp];
  float c_st[4] = {0.f, 0.f, 0.f, 0.f};
  f32x4 acc_pre = {0.f, 0.f, 0.f, 0.f};
  float gxv[4];
  if (L0){
#pragma unroll
    for (int rr = 0; rr < 4; ++rr)
      gxv[rr] = gx0[((size_t)(kg * 4 + rr)) * 2048 + colp];
  }

  for (int tick = 0; tick < 513; ++tick){
    const int t = tick - (L0 ? 0 : 1);
    const bool active = (t >= 0 && t < 512);
    f32x4 acc = {0.f, 0.f, 0.f, 0.f};
    if (active){
      if (L0){
        short8 av[16];
        ldA<16>(h0seq + (size_t)t * 8192 + r * 512 + kg * 8, av);
        vm0();
#pragma unroll
        for (int i = 0; i < 16; ++i)
          acc = __builtin_amdgcn_mfma_f32_16x16x32_bf16(av[i], breg[i], acc, 0, 0, 0);
      } else if (half == 0){
        acc = acc_pre;                                   // h0 part, prefetched
      } else {
        short8 av[16];
        ldA<16>(h1seq + (size_t)t * 8192 + r * 512 + kg * 8, av);
        vm0();
#pragma unroll
        for (int i = 0; i < 16; ++i)
          acc = __builtin_amdgcn_mfma_f32_16x16x32_bf16(av[i], breg[i], acc, 0, 0, 0);
        part[wave >> 1][lane] = acc;
      }
    }
    if (!L0) __syncthreads();
    if (active && (L0 || half == 0)){
      float v[4];
      if (L0){
#pragma unroll
        for (int rr = 0; rr < 4; ++rr) v[rr] = acc[rr] + gxv[rr];
      } else {
        f32x4 p2 = part[wave >> 1][lane];
#pragma unroll
        for (int rr = 0; rr < 4; ++rr) v[rr] = acc[rr] + p2[rr] + bias;
      }
      bf16* hrow = (L0 ? h0seq : h1seq) + (size_t)(t + 1) * 8192;
      float* hTp = (t == 511) ? (L0 ? hT0 : hT1) : nullptr;
      gate_tile(v, c_st, col, kg, jb, hrow, 512, hTp);
    }
    gbar_arrive(flags, (unsigned)(tick + 1));
    if (L0){
      if (tick + 1 < 512){
#pragma unroll
        for (int rr = 0; rr < 4; ++rr)
          gxv[rr] = gx0[((size_t)(tick + 1) * 16 + kg * 4 + rr) * 2048 + colp];
      }
      dpoll<0, 16>(flags, (unsigned)(tick + 1));         // own domain (sprint)
    } else {
      if (tick < 512){                                   // prefetch for t' = tick
        dpoll<0, 16>(flags, (unsigned)(tick + 1));       // c0 done -> h0 slot tick+1
        if (half == 0){
          short8 av[16];
          ldA<16>(h0seq + (size_t)(tick + 1) * 8192 + r * 512 + kg * 8, av);
          vm0();
          acc_pre = f32x4{0.f, 0.f, 0.f, 0.f};
#pragma unroll
          for (int i = 0; i < 16; ++i)
            acc_pre = __builtin_amdgcn_mfma_f32_16x16x32_bf16(av[i], breg[i], acc_pre, 0, 0, 0);
        }
      }
      dpoll<16, 32>(flags, (unsigned)(tick + 1));        // own domain
    }
  }
}

// ---- hd0/hd1 = tanh(fc1(hT)) into decoder seq slot 0 -----------------------
__global__ void k_hd(const float* __restrict__ hT0, const float* __restrict__ hT1,
                     const float* __restrict__ w, const float* __restrict__ b,
                     bf16* __restrict__ d0s0, bf16* __restrict__ d1s0)
{
  int gid = blockIdx.x * 256 + threadIdx.x;
  int sel = gid >> 14;
  int u = (gid >> 10) & 15, n = gid & 1023;
  const float* h = (sel ? hT1 : hT0) + u * 512;
  const float* wr = w + (size_t)n * 512;
  float s = b[n];
  for (int k = 0; k < 512; ++k) s += h[k] * wr[k];
  (sel ? d1s0 : d0s0)[(size_t)u * 1024 + n] = __float2bfloat16(tanhf(s));
}

// ---- decoder: d0 = WG 0-127 (leader 0), d1 = WG 128-255 (leader 128).
// d0: static h1 frags prefetched; d1: d0n frags prefetched (chase). ----------
__global__ __launch_bounds__(512, 2) void k_dec(
    const bf16* __restrict__ Wd0, const bf16* __restrict__ Wd1,
    const float* __restrict__ bd0, const float* __restrict__ bd1,
    const bf16* __restrict__ h1seq, bf16* d0seq, bf16* d1seq,
    unsigned* flags, unsigned* wm)
{
  const int wg = blockIdx.x, tid = threadIdx.x;
  const int lane = tid & 63, wave = tid >> 6;
  const int col = lane & 15, kg = lane >> 4, r = col;
  const bool L0 = wg < 128;
  const int grp = wave >> 2, q = wave & 3;
  const int tileIdx = (L0 ? wg : wg - 128) * 2 + grp;    // [0,256)
  const int colp = tileIdx * 16 + col;                   // [0,4096)
  const int jb = tileIdx * 4;
  unsigned* wm0 = wm;         // d0 replicas
  unsigned* wm1 = wm + 128;   // d1 replicas
  __shared__ f32x4 part[2][3][64];

  short8 breg[16];
#pragma unroll
  for (int i = 0; i < 16; ++i) breg[i] = short8{0,0,0,0,0,0,0,0};
  if (L0){
    const bf16* W = Wd0 + (size_t)colp * 1536 + q * 384;
#pragma unroll
    for (int i = 0; i < 12; ++i) breg[i] = *(const short8*)(W + i * 32 + kg * 8);
  } else {
    const bf16* W = Wd1 + (size_t)colp * 2048 + q * 512;
#pragma unroll
    for (int i = 0; i < 16; ++i) breg[i] = *(const short8*)(W + i * 32 + kg * 8);
  }
#pragma unroll
  for (int i = 0; i < 16; ++i) asm volatile("" : "+v"(breg[i]));

  const float bias = L0 ? bd0[colp] : bd1[colp];
  float c_st[4] = {0.f, 0.f, 0.f, 0.f};
  f32x4 acc_pre = {0.f, 0.f, 0.f, 0.f};

  // d0 prologue: prefetch static h1 fragments for t = 0 (h1seq is complete)
  if (L0){
    if (q == 0){
      short8 av[12];
      ldA<12>(h1seq + (size_t)1 * 8192 + r * 512 + kg * 8, av);
      vm0();
#pragma unroll
      for (int i = 0; i < 12; ++i)
        acc_pre = __builtin_amdgcn_mfma_f32_16x16x32_bf16(av[i], breg[i], acc_pre, 0, 0, 0);
    } else if (q == 1){
      short8 av[4];
      ldA<4>(h1seq + (size_t)1 * 8192 + r * 512 + kg * 8 + 384, av);
      vm0();
#pragma unroll
      for (int i = 0; i < 4; ++i)
        acc_pre = __builtin_amdgcn_mfma_f32_16x16x32_bf16(av[i], breg[i], acc_pre, 0, 0, 0);
    }
  }

  for (int tick = 0; tick < 513; ++tick){
    const int t = tick - (L0 ? 0 : 1);
    const bool active = (t >= 0 && t < 512);
    f32x4 acc = {0.f, 0.f, 0.f, 0.f};
    if (active){
      short8 av[16];
      if (L0){
        const bf16* d0p = d0seq + (size_t)t * 16384 + r * 1024 + kg * 8;
        if      (q == 0)  acc = acc_pre;                 // 12 static frags done
        else if (q == 1){
          ldA<8>(d0p, av);
          vm0();
          acc = acc_pre;                                 // 4 static frags done
#pragma unroll
          for (int i = 0; i < 8; ++i)
            acc = __builtin_amdgcn_mfma_f32_16x16x32_bf16(av[i], breg[4 + i], acc, 0, 0, 0);
        } else {
          ldA<12>(d0p + (q == 2 ? 256 : 640), av);
          vm0();
#pragma unroll
          for (int i = 0; i < 12; ++i)
            acc = __builtin_amdgcn_mfma_f32_16x16x32_bf16(av[i], breg[i], acc, 0, 0, 0);
        }
      } else {
        if (q < 2){
          acc = acc_pre;                                 // d0n half, prefetched
        } else {
          const bf16* d1c = d1seq + (size_t)t * 16384 + r * 1024 + kg * 8;
          ldA<16>(d1c + (q == 3 ? 512 : 0), av);
          vm0();
#pragma unroll
          for (int i = 0; i < 16; ++i)
            acc = __builtin_amdgcn_mfma_f32_16x16x32_bf16(av[i], breg[i], acc, 0, 0, 0);
        }
      }
      if (q != 0) part[grp][q - 1][lane] = acc;
    }
    __syncthreads();
    if (active && q == 0){
      f32x4 p0 = part[grp][0][lane], p1 = part[grp][1][lane], p2 = part[grp][2][lane];
      float v[4];
#pragma unroll
      for (int rr = 0; rr < 4; ++rr) v[rr] = acc[rr] + p0[rr] + p1[rr] + p2[rr] + bias;
      bf16* hrow = (L0 ? d0seq : d1seq) + (size_t)(t + 1) * 16384;
      gate_tile(v, c_st, col, kg, jb, hrow, 1024, nullptr);
    }
    gbar_arrive(flags, (unsigned)(tick + 1));
    if (L0){
      if (tick + 1 < 512){                               // prefetch static h1 for t'=tick+1
        if (q == 0){
          short8 av[12];
          ldA<12>(h1seq + (size_t)(tick + 2) * 8192 + r * 512 + kg * 8, av);
          vm0();
          acc_pre = f32x4{0.f, 0.f, 0.f, 0.f};
#pragma unroll
          for (int i = 0; i < 12; ++i)
            acc_pre = __builtin_amdgcn_mfma_f32_16x16x32_bf16(av[i], breg[i], acc_pre, 0, 0, 0);
        } else if (q == 1){
          short8 av[4];
          ldA<4>(h1seq + (size_t)(tick + 2) * 8192 + r * 512 + kg * 8 + 384, av);
          vm0();
          acc_pre = f32x4{0.f, 0.f, 0.f, 0.f};
#pragma unroll
          for (int i = 0; i < 4; ++i)
            acc_pre = __builtin_amdgcn_mfma_f32_16x16x32_bf16(av[i], breg[i], acc_pre, 0, 0, 0);
        }
      }
      if (wg == 0) lead_wait_pub<0, 128>(flags, wm0, (unsigned)(tick + 1));
      else         worker_wait(wm0, (unsigned)(tick + 1));
    } else {
      if (tick < 512){                                   // prefetch d0n for t'=tick
        worker_wait(wm0, (unsigned)(tick + 1));          // d0seq slot tick+1 ready
        if (q < 2){
          short8 av[16];
          ldA<16>(d0seq + (size_t)(tick + 1) * 16384 + r * 1024 + kg * 8 + q * 512, av);
          vm0();
          acc_pre = f32x4{0.f, 0.f, 0.f, 0.f};
#pragma unroll
          for (int i = 0; i < 16; ++i)
            acc_pre = __builtin_amdgcn_mfma_f32_16x16x32_bf16(av[i], breg[i], acc_pre, 0, 0, 0);
        }
      }
      if (wg == 128) lead_wait_pub<128, 128>(flags, wm1, (unsigned)(tick + 1));
      else           worker_wait(wm1, (unsigned)(tick + 1));
    }
  }
}

// ---- logits ---------------------------------------------------------------
__global__ __launch_bounds__(256) void k_logits(const bf16* __restrict__ d1seq,
                                                const bf16* __restrict__ ow,
                                                const float* __restrict__ ob,
                                                float* __restrict__ logits)
{
  const int u = blockIdx.x >> 4, tb = blockIdx.x & 15;
  __shared__ bf16 rows[32][1024];
  const int tid = threadIdx.x;
  for (int idx = tid; idx < 4096; idx += 256){
    int tl = idx >> 7, seg = idx & 127;
    *(short8*)&rows[tl][seg * 8] =
      *(const short8*)(d1seq + ((size_t)(tb * 32 + tl + 1) * 16 + u) * 1024 + seg * 8);
  }
  __syncthreads();
  for (int p = tid; p < 512; p += 256){
    int tl = p >> 4, o = p & 15;
    const bf16* wr = ow + (size_t)o * 1024;
    float s = 0.f;
    for (int k = 0; k < 1024; k += 8){
      short8 av = *(const short8*)&rows[tl][k];
      short8 wv = *(const short8*)(wr + k);
#pragma unroll
      for (int e = 0; e < 8; ++e) s += bfraw2f(av[e]) * bfraw2f(wv[e]);
    }
    logits[((size_t)u * 16 + o) * 512 + tb * 32 + tl] = s + ob[o];
  }
}

// ---- softmax over t per (u,o); out[t][u*16+o] ------------------------------
__global__ __launch_bounds__(256) void k_softmax(const float* __restrict__ logits,
                                                 float* __restrict__ out)
{
  const int u = blockIdx.x >> 4, o = blockIdx.x & 15;
  const float* L = logits + ((size_t)u * 16 + o) * 512;
  const int tid = threadIdx.x;
  float v0 = L[tid], v1 = L[tid + 256];
  float m = fmaxf(v0, v1);
  for (int d = 1; d < 64; d <<= 1) m = fmaxf(m, __shfl_xor(m, d));
  __shared__ float red[4], red2[4];
  if ((tid & 63) == 0) red[tid >> 6] = m;
  __syncthreads();
  m = fmaxf(fmaxf(red[0], red[1]), fmaxf(red[2], red[3]));
  float e0 = expf(v0 - m), e1 = expf(v1 - m);
  float s = e0 + e1;
  for (int d = 1; d < 64; d <<= 1) s += __shfl_xor(s, d);
  if ((tid & 63) == 0) red2[tid >> 6] = s;
  __syncthreads();
  s = red2[0] + red2[1] + red2[2] + red2[3];
  float inv = 1.f / s;
  out[(size_t)tid * 256 + u * 16 + o] = e0 * inv;
  out[(size_t)(tid + 256) * 256 + u * 16 + o] = e1 * inv;
}

// ---------------------------------------------------------------------------
extern "C" void kernel_launch(void* const* d_in, const int* in_sizes, int n_in,
                              void* d_out, int out_size, void* d_ws, size_t ws_size,
                              hipStream_t stream)
{
  const float* z      = (const float*)d_in[0];
  const float* fc0_w  = (const float*)d_in[1];
  const float* fc0_b  = (const float*)d_in[2];
  const float* fc1_w  = (const float*)d_in[3];
  const float* fc1_b  = (const float*)d_in[4];
  const float* c_wih0 = (const float*)d_in[5];
  const float* c_whh0 = (const float*)d_in[6];
  const float* c_b0   = (const float*)d_in[7];
  const float* c_wih1 = (const float*)d_in[8];
  const float* c_whh1 = (const float*)d_in[9];
  const float* c_b1   = (const float*)d_in[10];
  const float* d_wih0 = (const float*)d_in[11];
  const float* d_whh0 = (const float*)d_in[12];
  const float* d_b0   = (const float*)d_in[13];
  const float* d_wih1 = (const float*)d_in[14];
  const float* d_whh1 = (const float*)d_in[15];
  const float* d_b1   = (const float*)d_in[16];
  const float* out_w  = (const float*)d_in[17];
  const float* out_b  = (const float*)d_in[18];

  char* p = (char*)d_ws;
  auto alloc = [&](size_t bytes) -> char* {
    char* r = p; p += (bytes + 255) & ~(size_t)255; return r;
  };
  bf16*  Wgx0p  = (bf16*)alloc(2048ull * 512 * 2);
  bf16*  Wc0p   = (bf16*)alloc(2048ull * 512 * 2);
  bf16*  Wc1p   = (bf16*)alloc(2048ull * 1024 * 2);
  bf16*  Wd0p   = (bf16*)alloc(4096ull * 1536 * 2);
  bf16*  Wd1p   = (bf16*)alloc(4096ull * 2048 * 2);
  float* bc0p   = (float*)alloc(2048 * 4);
  float* bc1p   = (float*)alloc(2048 * 4);
  float* bd0p   = (float*)alloc(4096 * 4);
  float* bd1p   = (float*)alloc(4096 * 4);
  bf16*  outwbf = (bf16*)alloc(16384 * 2);
  bf16*  x      = (bf16*)alloc(8192ull * 512 * 2);
  float* gx0    = (float*)alloc(8192ull * 2048 * 4);
  bf16*  h0seq  = (bf16*)alloc(513ull * 16 * 512 * 2);
  bf16*  h1seq  = (bf16*)alloc(513ull * 16 * 512 * 2);
  bf16*  d0seq  = (bf16*)alloc(513ull * 16 * 1024 * 2);
  bf16*  d1seq  = (bf16*)alloc(513ull * 16 * 1024 * 2);
  float* hT0    = (float*)alloc(16 * 512 * 4);
  float* hT1    = (float*)alloc(16 * 512 * 4);
  float* logits = (float*)alloc(16ull * 16 * 512 * 4);
  unsigned* flagC = (unsigned*)alloc(64 * 4);
  unsigned* flagD = (unsigned*)alloc(256 * 4);
  unsigned* wmD   = (unsigned*)alloc(1024);
  if ((size_t)(p - (char*)d_ws) > ws_size){
    fprintf(stderr, "kernel_launch: ws too small (%zu needed, %zu given)\n",
            (size_t)(p - (char*)d_ws), ws_size);
    return;
  }

  hipMemsetAsync(flagC, 0, 64 * 4, stream);
  hipMemsetAsync(flagD, 0, 256 * 4, stream);
  hipMemsetAsync(wmD, 0, 1024, stream);
  hipMemsetAsync(h0seq, 0, 16 * 512 * 2, stream);
  hipMemsetAsync(h1seq, 0, 16 * 512 * 2, stream);

  k_prep_w<<<2048, 256, 0, stream>>>(c_wih0, nullptr, 512, 0,   512, Wgx0p);
  k_prep_w<<<2048, 256, 0, stream>>>(c_whh0, nullptr, 512, 0,   512, Wc0p);
  k_prep_w<<<2048, 256, 0, stream>>>(c_wih1, c_whh1, 512, 512,  512, Wc1p);
  k_prep_w<<<4096, 256, 0, stream>>>(d_wih0, d_whh0, 512, 1024, 1024, Wd0p);
  k_prep_w<<<4096, 256, 0, stream>>>(d_wih1, d_whh1, 1024, 1024, 1024, Wd1p);
  k_prep_b<<<8,  256, 0, stream>>>(c_b0, 512,  bc0p);
  k_prep_b<<<8,  256, 0, stream>>>(c_b1, 512,  bc1p);
  k_prep_b<<<16, 256, 0, stream>>>(d_b0, 1024, bd0p);
  k_prep_b<<<16, 256, 0, stream>>>(d_b1, 1024, bd1p);
  k_conv_bf<<<64, 256, 0, stream>>>(out_w, outwbf, 16 * 1024);

  k_fc0<<<8192, 256, 0, stream>>>(z, fc0_w, fc0_b, x);
  k_gemm_gx0<<<1024, 256, 0, stream>>>(x, Wgx0p, bc0p, gx0);

  k_cond<<<48, 512, 0, stream>>>(Wc0p, Wc1p, bc1p, gx0, h0seq, h1seq, hT0, hT1, flagC);
  k_hd<<<128, 256, 0, stream>>>(hT0, hT1, fc1_w, fc1_b, d0seq, d1seq);
  k_dec<<<256, 512, 0, stream>>>(Wd0p, Wd1p, bd0p, bd1p, h1seq, d0seq, d1seq, flagD, wmD);

  k_logits<<<256, 256, 0, stream>>>(d1seq, outwbf, out_b, logits);
  k_softmax<<<256, 256, 0, stream>>>(logits, (float*)d_out);
}

// Round 14
// 6830.671 us; speedup vs baseline: 1.2260x; 1.0360x over previous
//
#include <hip/hip_runtime.h>
#include <hip/hip_bf16.h>
#include <cstdio>

// ---------------------------------------------------------------------------
// HierarchicalDecoder: 4-layer LSTM stack, T=512, batch U=16.
// v13 = v10 verbatim (best measured: 6869us). Write-once h-state, sc0sc1
// write-through stores, cached reads, no per-tick invalidate, layer-local
// domains, hierarchical leader barrier, cross-domain operand prefetch
// between arrive and own-wait, 8-way replicated watermark lines.
// ---------------------------------------------------------------------------

typedef __attribute__((ext_vector_type(8))) short short8;   // 8 x bf16
typedef __attribute__((ext_vector_type(4))) float f32x4;
typedef __attribute__((ext_vector_type(2))) unsigned int u32x2;
using bf16 = __hip_bfloat16;

__device__ __forceinline__ float bfraw2f(short s){
  return __uint_as_float(((unsigned)(unsigned short)s) << 16);
}
__device__ __forceinline__ unsigned bfbits(float f){
  __hip_bfloat16 h = __float2bfloat16(f);
  return (unsigned)*reinterpret_cast<unsigned short*>(&h);
}

// ---- barrier primitives ----------------------------------------------------
__device__ __forceinline__ void gbar_arrive(unsigned* flags, unsigned gen){
  asm volatile("s_waitcnt vmcnt(0)" ::: "memory");   // h-stores completed at LLC
  __syncthreads();                                   // all waves drained
  if (threadIdx.x == 0)
    __hip_atomic_store(&flags[blockIdx.x], gen,
                       __ATOMIC_RELAXED, __HIP_MEMORY_SCOPE_AGENT);
}
// leader: poll own-domain flags, then immediately publish to 8 replicas
template<int BASE, int N>
__device__ __forceinline__ void lead_wait_pub(const unsigned* flags, unsigned* wm8,
                                              unsigned gen){
  if (threadIdx.x < 64){
    const int l = threadIdx.x;
    for (;;){
      bool ok = true;
#pragma unroll
      for (int k = 0; k < (N + 63) / 64; ++k){
        int idx = l + k * 64;
        if (idx < N)
          ok &= (__hip_atomic_load(&flags[BASE + idx], __ATOMIC_RELAXED,
                                   __HIP_MEMORY_SCOPE_AGENT) >= gen);
      }
      if (__all(ok)) break;
    }
    if (l < 8)
      __hip_atomic_store(&wm8[l * 16], gen, __ATOMIC_RELAXED,
                         __HIP_MEMORY_SCOPE_AGENT);
  }
  __syncthreads();
}
__device__ __forceinline__ void worker_wait(const unsigned* wm8, unsigned gen){
  if (threadIdx.x == 0){
    const unsigned* p = &wm8[(blockIdx.x & 7) * 16];
    while (__hip_atomic_load(p, __ATOMIC_RELAXED, __HIP_MEMORY_SCOPE_AGENT) < gen)
      __builtin_amdgcn_s_sleep(1);
  }
  __syncthreads();
}

// ---- A-operand loads: plain cached (write-once protocol makes them safe) ---
template<int N>
__device__ __forceinline__ void ldA(const bf16* base, short8* av){
#pragma unroll
  for (int i = 0; i < N; ++i)
    av[i] = *(const short8*)(base + i * 32);
}
__device__ __forceinline__ void vm0(){
  asm volatile("s_waitcnt vmcnt(0)" ::: "memory");
  __builtin_amdgcn_sched_barrier(0);
}

// ---- LSTM gate math for one 16-col tile; packed 8B write-through h-store ---
__device__ __forceinline__ void gate_tile(const float v[4], float* c_st,
                                          int col, int kg, int jb,
                                          bf16* hrow, int Hl, float* hTrow)
{
  const int g = col & 3;
#pragma unroll
  for (int rr = 0; rr < 4; ++rr){
    float a = (g == 2) ? tanhf(v[rr]) : 1.f / (1.f + expf(-v[rr]));
    float x1 = __shfl_xor(a, 1);
    float x2 = __shfl_xor(a, 2);
    float x3 = __shfl_xor(x1, 2);
    float cn = x1 * c_st[rr] + a * x2;   // valid on g==0 lanes
    float hn = x3 * tanhf(cn);           // sig(o)*tanh(c)
    c_st[rr] = cn;
    float h4 = __shfl_xor(hn, 4), h8 = __shfl_xor(hn, 8), h12 = __shfl_xor(hn, 12);
    if (col == 0){
      int u = kg * 4 + rr;
      u32x2 pk;
      pk.x = bfbits(hn) | (bfbits(h4) << 16);
      pk.y = bfbits(h8) | (bfbits(h12) << 16);
      bf16* p = hrow + (size_t)u * Hl + jb;
      asm volatile("global_store_dwordx2 %0, %1, off sc0 sc1"
                   :: "v"(p), "v"(pk) : "memory");
      if (hTrow){
        f32x4 hv = {hn, h4, h8, h12};
        *(f32x4*)(hTrow + (size_t)u * Hl + jb) = hv;
      }
    }
  }
}

// ---- weight prep: permute rows to col'=4j+g, concat K, cvt bf16 ------------
__global__ void k_prep_w(const float* __restrict__ srcA, const float* __restrict__ srcB,
                         int K1, int K2, int H, bf16* __restrict__ dst)
{
  const int row = blockIdx.x;
  const int j = row >> 2, g = row & 3;
  const int Kt = K1 + K2;
  const float* sA = srcA + (size_t)(g * H + j) * K1;
  const float* sB = srcB ? srcB + (size_t)(g * H + j) * K2 : nullptr;
  bf16* d = dst + (size_t)row * Kt;
  for (int k = threadIdx.x; k < Kt; k += blockDim.x)
    d[k] = __float2bfloat16(k < K1 ? sA[k] : sB[k - K1]);
}

__global__ void k_prep_b(const float* __restrict__ src, int H, float* __restrict__ dst){
  int i = blockIdx.x * blockDim.x + threadIdx.x;
  if (i < 4 * H) dst[i] = src[(i & 3) * H + (i >> 2)];
}

__global__ void k_conv_bf(const float* __restrict__ src, bf16* __restrict__ dst, int n){
  int i = blockIdx.x * blockDim.x + threadIdx.x;
  if (i < n) dst[i] = __float2bfloat16(src[i]);
}

// ---- fc0 -------------------------------------------------------------------
__global__ void k_fc0(const float* __restrict__ z, const float* __restrict__ w,
                      const float* __restrict__ b, bf16* __restrict__ x)
{
  const int m = blockIdx.x;
  const int t = m >> 4, u = m & 15;
  const float* zr = z + (size_t)t * 512 + u * 32;
  float zv[32];
#pragma unroll
  for (int k = 0; k < 32; ++k) zv[k] = zr[k];
  for (int n = threadIdx.x; n < 512; n += 256){
    const float* wr = w + n * 32;
    float s = b[n];
#pragma unroll
    for (int k = 0; k < 32; ++k) s += zv[k] * wr[k];
    x[(size_t)m * 512 + n] = __float2bfloat16(tanhf(s));
  }
}

// ---- big GEMM for gx0 = x @ Wgx0'^T + bc0' ---------------------------------
__device__ __forceinline__ void gload16(const void* g, void* lds_wave_base){
  __builtin_amdgcn_global_load_lds((const __attribute__((address_space(1))) void*)g,
                                   (__attribute__((address_space(3))) void*)lds_wave_base,
                                   16, 0, 0);
}

__global__ __launch_bounds__(256) void k_gemm_gx0(const bf16* __restrict__ A,
                                                  const bf16* __restrict__ W,
                                                  const float* __restrict__ bias,
                                                  float* __restrict__ C)
{
  __shared__ bf16 Al[128 * 64];
  __shared__ bf16 Bl[128 * 64];
  const int tid = threadIdx.x, lane = tid & 63, wave = tid >> 6;
  const int bm = blockIdx.x & 63, bn = blockIdx.x >> 6;
  const int wm = wave >> 1, wn = wave & 1;
  const int col = lane & 15, kg = lane >> 4;

  f32x4 acc[4][4];
#pragma unroll
  for (int i = 0; i < 4; ++i)
#pragma unroll
    for (int q = 0; q < 4; ++q) acc[i][q] = f32x4{0.f, 0.f, 0.f, 0.f};

  const int r = tid >> 3, c8 = (tid & 7) * 8;
  for (int k0 = 0; k0 < 512; k0 += 64){
    const bf16* ga = A + (size_t)(bm * 128 + r) * 512 + k0 + c8;
    const bf16* gb = W + (size_t)(bn * 128 + r) * 512 + k0 + c8;
#pragma unroll
    for (int i = 0; i < 4; ++i){
      gload16(ga + (size_t)32 * i * 512, (char*)Al + (size_t)i * 4096 + wave * 1024);
      gload16(gb + (size_t)32 * i * 512, (char*)Bl + (size_t)i * 4096 + wave * 1024);
    }
    __syncthreads();
#pragma unroll
    for (int kb = 0; kb < 2; ++kb){
      short8 af[4], bfr[4];
#pragma unroll
      for (int i = 0; i < 4; ++i)
        af[i] = *(const short8*)&Al[(wm * 64 + i * 16 + col) * 64 + kb * 32 + kg * 8];
#pragma unroll
      for (int i = 0; i < 4; ++i)
        bfr[i] = *(const short8*)&Bl[(wn * 64 + i * 16 + col) * 64 + kb * 32 + kg * 8];
#pragma unroll
      for (int i = 0; i < 4; ++i)
#pragma unroll
        for (int q = 0; q < 4; ++q)
          acc[i][q] = __builtin_amdgcn_mfma_f32_16x16x32_bf16(af[i], bfr[q], acc[i][q], 0, 0, 0);
    }
    __syncthreads();
  }
#pragma unroll
  for (int i = 0; i < 4; ++i)
#pragma unroll
    for (int q = 0; q < 4; ++q){
      int cc = bn * 128 + wn * 64 + q * 16 + col;
      float bv = bias[cc];
#pragma unroll
      for (int rr = 0; rr < 4; ++rr){
        int rrow = bm * 128 + wm * 64 + i * 16 + kg * 4 + rr;
        C[(size_t)rrow * 2048 + cc] = acc[i][q][rr] + bv;
      }
    }
}

// ---- conductor: c0 = WG 0-15 (leader 0), c1 = WG 16-47 (leader 16).
// c1 half0 (h0 operand) prefetched between arrive and own-wait. -------------
__global__ __launch_bounds__(512, 2) void k_cond(
    const bf16* __restrict__ Wc0, const bf16* __restrict__ Wc1,
    const float* __restrict__ bc1, const float* __restrict__ gx0,
    bf16* h0seq, bf16* h1seq, float* hT0, float* hT1,
    unsigned* flags, unsigned* wm)
{
  const int wg = blockIdx.x, tid = threadIdx.x;
  const int lane = tid & 63, wave = tid >> 6;
  const int col = lane & 15, kg = lane >> 4;
  const int r = col;
  const bool L0 = wg < 16;
  unsigned* wm0 = wm;         // c0 replicas
  unsigned* wm1 = wm + 128;   // c1 replicas
  __shared__ f32x4 part[4][64];

  int tileIdx, half = 0;
  if (L0) tileIdx = wg * 8 + wave;                       // [0,128)
  else  { tileIdx = (wg - 16) * 4 + (wave >> 1); half = wave & 1; }
  const int colp = tileIdx * 16 + col;                   // [0,2048)
  const int jb = tileIdx * 4;

  short8 breg[16];
  {
    const bf16* W = L0 ? (Wc0 + (size_t)colp * 512)
                       : (Wc1 + (size_t)colp * 1024 + half * 512);
#pragma unroll
    for (int i = 0; i < 16; ++i) breg[i] = *(const short8*)(W + i * 32 + kg * 8);
  }
#pragma unroll
  for (int i = 0; i < 16; ++i) asm volatile("" : "+v"(breg[i]));

  const float bias = L0 ? 0.f : bc1[colp];
  float c_st[4] = {0.f, 0.f, 0.f, 0.f};
  f32x4 acc_pre = {0.f, 0.f, 0.f, 0.f};
  float gxv[4];
  if (L0){
#pragma unroll
    for (int rr = 0; rr < 4; ++rr)
      gxv[rr] = gx0[((size_t)(kg * 4 + rr)) * 2048 + colp];
  }

  for (int tick = 0; tick < 513; ++tick){
    const int t = tick - (L0 ? 0 : 1);
    const bool active = (t >= 0 && t < 512);
    f32x4 acc = {0.f, 0.f, 0.f, 0.f};
    if (active){
      if (L0){
        short8 av[16];
        ldA<16>(h0seq + (size_t)t * 8192 + r * 512 + kg * 8, av);
        vm0();
#pragma unroll
        for (int i = 0; i < 16; ++i)
          acc = __builtin_amdgcn_mfma_f32_16x16x32_bf16(av[i], breg[i], acc, 0, 0, 0);
      } else if (half == 0){
        acc = acc_pre;                                   // h0 part, prefetched
      } else {
        short8 av[16];
        ldA<16>(h1seq + (size_t)t * 8192 + r * 512 + kg * 8, av);
        vm0();
#pragma unroll
        for (int i = 0; i < 16; ++i)
          acc = __builtin_amdgcn_mfma_f32_16x16x32_bf16(av[i], breg[i], acc, 0, 0, 0);
        part[wave >> 1][lane] = acc;
      }
    }
    if (!L0) __syncthreads();
    if (active && (L0 || half == 0)){
      float v[4];
      if (L0){
#pragma unroll
        for (int rr = 0; rr < 4; ++rr) v[rr] = acc[rr] + gxv[rr];
      } else {
        f32x4 p2 = part[wave >> 1][lane];
#pragma unroll
        for (int rr = 0; rr < 4; ++rr) v[rr] = acc[rr] + p2[rr] + bias;
      }
      bf16* hrow = (L0 ? h0seq : h1seq) + (size_t)(t + 1) * 8192;
      float* hTp = (t == 511) ? (L0 ? hT0 : hT1) : nullptr;
      gate_tile(v, c_st, col, kg, jb, hrow, 512, hTp);
    }
    gbar_arrive(flags, (unsigned)(tick + 1));
    if (L0){
      if (tick + 1 < 512){
#pragma unroll
        for (int rr = 0; rr < 4; ++rr)
          gxv[rr] = gx0[((size_t)(tick + 1) * 16 + kg * 4 + rr) * 2048 + colp];
      }
      if (wg == 0) lead_wait_pub<0, 16>(flags, wm0, (unsigned)(tick + 1));
      else         worker_wait(wm0, (unsigned)(tick + 1));
    } else {
      if (tick < 512){                                   // prefetch for t' = tick
        worker_wait(wm0, (unsigned)(tick + 1));          // h0 slot tick+1 ready
        if (half == 0){
          short8 av[16];
          ldA<16>(h0seq + (size_t)(tick + 1) * 8192 + r * 512 + kg * 8, av);
          vm0();
          acc_pre = f32x4{0.f, 0.f, 0.f, 0.f};
#pragma unroll
          for (int i = 0; i < 16; ++i)
            acc_pre = __builtin_amdgcn_mfma_f32_16x16x32_bf16(av[i], breg[i], acc_pre, 0, 0, 0);
        }
      }
      if (wg == 16) lead_wait_pub<16, 32>(flags, wm1, (unsigned)(tick + 1));
      else          worker_wait(wm1, (unsigned)(tick + 1));
    }
  }
}

// ---- hd0/hd1 = tanh(fc1(hT)) into decoder seq slot 0 -----------------------
__global__ void k_hd(const float* __restrict__ hT0, const float* __restrict__ hT1,
                     const float* __restrict__ w, const float* __restrict__ b,
                     bf16* __restrict__ d0s0, bf16* __restrict__ d1s0)
{
  int gid = blockIdx.x * 256 + threadIdx.x;
  int sel = gid >> 14;
  int u = (gid >> 10) & 15, n = gid & 1023;
  const float* h = (sel ? hT1 : hT0) + u * 512;
  const float* wr = w + (size_t)n * 512;
  float s = b[n];
  for (int k = 0; k < 512; ++k) s += h[k] * wr[k];
  (sel ? d1s0 : d0s0)[(size_t)u * 1024 + n] = __float2bfloat16(tanhf(s));
}

// ---- decoder: d0 = WG 0-127 (leader 0), d1 = WG 128-255 (leader 128).
// d0: static h1 frags prefetched; d1: d0n frags prefetched (chase). ----------
__global__ __launch_bounds__(512, 2) void k_dec(
    const bf16* __restrict__ Wd0, const bf16* __restrict__ Wd1,
    const float* __restrict__ bd0, const float* __restrict__ bd1,
    const bf16* __restrict__ h1seq, bf16* d0seq, bf16* d1seq,
    unsigned* flags, unsigned* wm)
{
  const int wg = blockIdx.x, tid = threadIdx.x;
  const int lane = tid & 63, wave = tid >> 6;
  const int col = lane & 15, kg = lane >> 4, r = col;
  const bool L0 = wg < 128;
  const int grp = wave >> 2, q = wave & 3;
  const int tileIdx = (L0 ? wg : wg - 128) * 2 + grp;    // [0,256)
  const int colp = tileIdx * 16 + col;                   // [0,4096)
  const int jb = tileIdx * 4;
  unsigned* wm0 = wm;         // d0 replicas
  unsigned* wm1 = wm + 128;   // d1 replicas
  __shared__ f32x4 part[2][3][64];

  short8 breg[16];
#pragma unroll
  for (int i = 0; i < 16; ++i) breg[i] = short8{0,0,0,0,0,0,0,0};
  if (L0){
    const bf16* W = Wd0 + (size_t)colp * 1536 + q * 384;
#pragma unroll
    for (int i = 0; i < 12; ++i) breg[i] = *(const short8*)(W + i * 32 + kg * 8);
  } else {
    const bf16* W = Wd1 + (size_t)colp * 2048 + q * 512;
#pragma unroll
    for (int i = 0; i < 16; ++i) breg[i] = *(const short8*)(W + i * 32 + kg * 8);
  }
#pragma unroll
  for (int i = 0; i < 16; ++i) asm volatile("" : "+v"(breg[i]));

  const float bias = L0 ? bd0[colp] : bd1[colp];
  float c_st[4] = {0.f, 0.f, 0.f, 0.f};
  f32x4 acc_pre = {0.f, 0.f, 0.f, 0.f};

  // d0 prologue: prefetch static h1 fragments for t = 0 (h1seq is complete)
  if (L0){
    if (q == 0){
      short8 av[12];
      ldA<12>(h1seq + (size_t)1 * 8192 + r * 512 + kg * 8, av);
      vm0();
#pragma unroll
      for (int i = 0; i < 12; ++i)
        acc_pre = __builtin_amdgcn_mfma_f32_16x16x32_bf16(av[i], breg[i], acc_pre, 0, 0, 0);
    } else if (q == 1){
      short8 av[4];
      ldA<4>(h1seq + (size_t)1 * 8192 + r * 512 + kg * 8 + 384, av);
      vm0();
#pragma unroll
      for (int i = 0; i < 4; ++i)
        acc_pre = __builtin_amdgcn_mfma_f32_16x16x32_bf16(av[i], breg[i], acc_pre, 0, 0, 0);
    }
  }

  for (int tick = 0; tick < 513; ++tick){
    const int t = tick - (L0 ? 0 : 1);
    const bool active = (t >= 0 && t < 512);
    f32x4 acc = {0.f, 0.f, 0.f, 0.f};
    if (active){
      short8 av[16];
      if (L0){
        const bf16* d0p = d0seq + (size_t)t * 16384 + r * 1024 + kg * 8;
        if      (q == 0)  acc = acc_pre;                 // 12 static frags done
        else if (q == 1){
          ldA<8>(d0p, av);
          vm0();
          acc = acc_pre;                                 // 4 static frags done
#pragma unroll
          for (int i = 0; i < 8; ++i)
            acc = __builtin_amdgcn_mfma_f32_16x16x32_bf16(av[i], breg[4 + i], acc, 0, 0, 0);
        } else {
          ldA<12>(d0p + (q == 2 ? 256 : 640), av);
          vm0();
#pragma unroll
          for (int i = 0; i < 12; ++i)
            acc = __builtin_amdgcn_mfma_f32_16x16x32_bf16(av[i], breg[i], acc, 0, 0, 0);
        }
      } else {
        if (q < 2){
          acc = acc_pre;                                 // d0n half, prefetched
        } else {
          const bf16* d1c = d1seq + (size_t)t * 16384 + r * 1024 + kg * 8;
          ldA<16>(d1c + (q == 3 ? 512 : 0), av);
          vm0();
#pragma unroll
          for (int i = 0; i < 16; ++i)
            acc = __builtin_amdgcn_mfma_f32_16x16x32_bf16(av[i], breg[i], acc, 0, 0, 0);
        }
      }
      if (q != 0) part[grp][q - 1][lane] = acc;
    }
    __syncthreads();
    if (active && q == 0){
      f32x4 p0 = part[grp][0][lane], p1 = part[grp][1][lane], p2 = part[grp][2][lane];
      float v[4];
#pragma unroll
      for (int rr = 0; rr < 4; ++rr) v[rr] = acc[rr] + p0[rr] + p1[rr] + p2[rr] + bias;
      bf16* hrow = (L0 ? d0seq : d1seq) + (size_t)(t + 1) * 16384;
      gate_tile(v, c_st, col, kg, jb, hrow, 1024, nullptr);
    }
    gbar_arrive(flags, (unsigned)(tick + 1));
    if (L0){
      if (tick + 1 < 512){                               // prefetch static h1 for t'=tick+1
        if (q == 0){
          short8 av[12];
          ldA<12>(h1seq + (size_t)(tick + 2) * 8192 + r * 512 + kg * 8, av);
          vm0();
          acc_pre = f32x4{0.f, 0.f, 0.f, 0.f};
#pragma unroll
          for (int i = 0; i < 12; ++i)
            acc_pre = __builtin_amdgcn_mfma_f32_16x16x32_bf16(av[i], breg[i], acc_pre, 0, 0, 0);
        } else if (q == 1){
          short8 av[4];
          ldA<4>(h1seq + (size_t)(tick + 2) * 8192 + r * 512 + kg * 8 + 384, av);
          vm0();
          acc_pre = f32x4{0.f, 0.f, 0.f, 0.f};
#pragma unroll
          for (int i = 0; i < 4; ++i)
            acc_pre = __builtin_amdgcn_mfma_f32_16x16x32_bf16(av[i], breg[i], acc_pre, 0, 0, 0);
        }
      }
      if (wg == 0) lead_wait_pub<0, 128>(flags, wm0, (unsigned)(tick + 1));
      else         worker_wait(wm0, (unsigned)(tick + 1));
    } else {
      if (tick < 512){                                   // prefetch d0n for t'=tick
        worker_wait(wm0, (unsigned)(tick + 1));          // d0seq slot tick+1 ready
        if (q < 2){
          short8 av[16];
          ldA<16>(d0seq + (size_t)(tick + 1) * 16384 + r * 1024 + kg * 8 + q * 512, av);
          vm0();
          acc_pre = f32x4{0.f, 0.f, 0.f, 0.f};
#pragma unroll
          for (int i = 0; i < 16; ++i)
            acc_pre = __builtin_amdgcn_mfma_f32_16x16x32_bf16(av[i], breg[i], acc_pre, 0, 0, 0);
        }
      }
      if (wg == 128) lead_wait_pub<128, 128>(flags, wm1, (unsigned)(tick + 1));
      else           worker_wait(wm1, (unsigned)(tick + 1));
    }
  }
}

// ---- logits ---------------------------------------------------------------
__global__ __launch_bounds__(256) void k_logits(const bf16* __restrict__ d1seq,
                                                const bf16* __restrict__ ow,
                                                const float* __restrict__ ob,
                                                float* __restrict__ logits)
{
  const int u = blockIdx.x >> 4, tb = blockIdx.x & 15;
  __shared__ bf16 rows[32][1024];
  const int tid = threadIdx.x;
  for (int idx = tid; idx < 4096; idx += 256){
    int tl = idx >> 7, seg = idx & 127;
    *(short8*)&rows[tl][seg * 8] =
      *(const short8*)(d1seq + ((size_t)(tb * 32 + tl + 1) * 16 + u) * 1024 + seg * 8);
  }
  __syncthreads();
  for (int p = tid; p < 512; p += 256){
    int tl = p >> 4, o = p & 15;
    const bf16* wr = ow + (size_t)o * 1024;
    float s = 0.f;
    for (int k = 0; k < 1024; k += 8){
      short8 av = *(const short8*)&rows[tl][k];
      short8 wv = *(const short8*)(wr + k);
#pragma unroll
      for (int e = 0; e < 8; ++e) s += bfraw2f(av[e]) * bfraw2f(wv[e]);
    }
    logits[((size_t)u * 16 + o) * 512 + tb * 32 + tl] = s + ob[o];
  }
}

// ---- softmax over t per (u,o); out[t][u*16+o] ------------------------------
__global__ __launch_bounds__(256) void k_softmax(const float* __restrict__ logits,
                                                 float* __restrict__ out)
{
  const int u = blockIdx.x >> 4, o = blockIdx.x & 15;
  const float* L = logits + ((size_t)u * 16 + o) * 512;
  const int tid = threadIdx.x;
  float v0 = L[tid], v1 = L[tid + 256];
  float m = fmaxf(v0, v1);
  for (int d = 1; d < 64; d <<= 1) m = fmaxf(m, __shfl_xor(m, d));
  __shared__ float red[4], red2[4];
  if ((tid & 63) == 0) red[tid >> 6] = m;
  __syncthreads();
  m = fmaxf(fmaxf(red[0], red[1]), fmaxf(red[2], red[3]));
  float e0 = expf(v0 - m), e1 = expf(v1 - m);
  float s = e0 + e1;
  for (int d = 1; d < 64; d <<= 1) s += __shfl_xor(s, d);
  if ((tid & 63) == 0) red2[tid >> 6] = s;
  __syncthreads();
  s = red2[0] + red2[1] + red2[2] + red2[3];
  float inv = 1.f / s;
  out[(size_t)tid * 256 + u * 16 + o] = e0 * inv;
  out[(size_t)(tid + 256) * 256 + u * 16 + o] = e1 * inv;
}

// ---------------------------------------------------------------------------
extern "C" void kernel_launch(void* const* d_in, const int* in_sizes, int n_in,
                              void* d_out, int out_size, void* d_ws, size_t ws_size,
                              hipStream_t stream)
{
  const float* z      = (const float*)d_in[0];
  const float* fc0_w  = (const float*)d_in[1];
  const float* fc0_b  = (const float*)d_in[2];
  const float* fc1_w  = (const float*)d_in[3];
  const float* fc1_b  = (const float*)d_in[4];
  const float* c_wih0 = (const float*)d_in[5];
  const float* c_whh0 = (const float*)d_in[6];
  const float* c_b0   = (const float*)d_in[7];
  const float* c_wih1 = (const float*)d_in[8];
  const float* c_whh1 = (const float*)d_in[9];
  const float* c_b1   = (const float*)d_in[10];
  const float* d_wih0 = (const float*)d_in[11];
  const float* d_whh0 = (const float*)d_in[12];
  const float* d_b0   = (const float*)d_in[13];
  const float* d_wih1 = (const float*)d_in[14];
  const float* d_whh1 = (const float*)d_in[15];
  const float* d_b1   = (const float*)d_in[16];
  const float* out_w  = (const float*)d_in[17];
  const float* out_b  = (const float*)d_in[18];

  char* p = (char*)d_ws;
  auto alloc = [&](size_t bytes) -> char* {
    char* r = p; p += (bytes + 255) & ~(size_t)255; return r;
  };
  bf16*  Wgx0p  = (bf16*)alloc(2048ull * 512 * 2);
  bf16*  Wc0p   = (bf16*)alloc(2048ull * 512 * 2);
  bf16*  Wc1p   = (bf16*)alloc(2048ull * 1024 * 2);
  bf16*  Wd0p   = (bf16*)alloc(4096ull * 1536 * 2);
  bf16*  Wd1p   = (bf16*)alloc(4096ull * 2048 * 2);
  float* bc0p   = (float*)alloc(2048 * 4);
  float* bc1p   = (float*)alloc(2048 * 4);
  float* bd0p   = (float*)alloc(4096 * 4);
  float* bd1p   = (float*)alloc(4096 * 4);
  bf16*  outwbf = (bf16*)alloc(16384 * 2);
  bf16*  x      = (bf16*)alloc(8192ull * 512 * 2);
  float* gx0    = (float*)alloc(8192ull * 2048 * 4);
  bf16*  h0seq  = (bf16*)alloc(513ull * 16 * 512 * 2);
  bf16*  h1seq  = (bf16*)alloc(513ull * 16 * 512 * 2);
  bf16*  d0seq  = (bf16*)alloc(513ull * 16 * 1024 * 2);
  bf16*  d1seq  = (bf16*)alloc(513ull * 16 * 1024 * 2);
  float* hT0    = (float*)alloc(16 * 512 * 4);
  float* hT1    = (float*)alloc(16 * 512 * 4);
  float* logits = (float*)alloc(16ull * 16 * 512 * 4);
  unsigned* flagC = (unsigned*)alloc(64 * 4);
  unsigned* flagD = (unsigned*)alloc(256 * 4);
  unsigned* wmC   = (unsigned*)alloc(1024);
  unsigned* wmD   = (unsigned*)alloc(1024);
  if ((size_t)(p - (char*)d_ws) > ws_size){
    fprintf(stderr, "kernel_launch: ws too small (%zu needed, %zu given)\n",
            (size_t)(p - (char*)d_ws), ws_size);
    return;
  }

  hipMemsetAsync(flagC, 0, 64 * 4, stream);
  hipMemsetAsync(flagD, 0, 256 * 4, stream);
  hipMemsetAsync(wmC, 0, 1024, stream);
  hipMemsetAsync(wmD, 0, 1024, stream);
  hipMemsetAsync(h0seq, 0, 16 * 512 * 2, stream);
  hipMemsetAsync(h1seq, 0, 16 * 512 * 2, stream);

  k_prep_w<<<2048, 256, 0, stream>>>(c_wih0, nullptr, 512, 0,   512, Wgx0p);
  k_prep_w<<<2048, 256, 0, stream>>>(c_whh0, nullptr, 512, 0,   512, Wc0p);
  k_prep_w<<<2048, 256, 0, stream>>>(c_wih1, c_whh1, 512, 512,  512, Wc1p);
  k_prep_w<<<4096, 256, 0, stream>>>(d_wih0, d_whh0, 512, 1024, 1024, Wd0p);
  k_prep_w<<<4096, 256, 0, stream>>>(d_wih1, d_whh1, 1024, 1024, 1024, Wd1p);
  k_prep_b<<<8,  256, 0, stream>>>(c_b0, 512,  bc0p);
  k_prep_b<<<8,  256, 0, stream>>>(c_b1, 512,  bc1p);
  k_prep_b<<<16, 256, 0, stream>>>(d_b0, 1024, bd0p);
  k_prep_b<<<16, 256, 0, stream>>>(d_b1, 1024, bd1p);
  k_conv_bf<<<64, 256, 0, stream>>>(out_w, outwbf, 16 * 1024);

  k_fc0<<<8192, 256, 0, stream>>>(z, fc0_w, fc0_b, x);
  k_gemm_gx0<<<1024, 256, 0, stream>>>(x, Wgx0p, bc0p, gx0);

  k_cond<<<48, 512, 0, stream>>>(Wc0p, Wc1p, bc1p, gx0, h0seq, h1seq, hT0, hT1, flagC, wmC);
  k_hd<<<128, 256, 0, stream>>>(hT0, hT1, fc1_w, fc1_b, d0seq, d1seq);
  k_dec<<<256, 512, 0, stream>>>(Wd0p, Wd1p, bd0p, bd1p, h1seq, d0seq, d1seq, flagD, wmD);

  k_logits<<<256, 256, 0, stream>>>(d1seq, outwbf, out_b, logits);
  k_softmax<<<256, 256, 0, stream>>>(logits, (float*)d_out);
}